// Round 3
// baseline (201.341 us; speedup 1.0000x reference)
//
#include <hip/hip_runtime.h>

typedef short short8 __attribute__((ext_vector_type(8)));
typedef float f32x4 __attribute__((ext_vector_type(4)));

#define HW 3136   // 56*56
#define NPX 12544 // B*HW
#define WSTR 836  // wgt pixel stride in bf16 units: 16 groups * 52 + 4 pad

__device__ __forceinline__ unsigned short f2bf(float f) {
    union { float f; unsigned int u; } v; v.f = f;
    unsigned int u = v.u;
    u += 0x7FFFu + ((u >> 16) & 1u);
    return (unsigned short)(u >> 16);
}

__device__ __forceinline__ float fget(const float4& v, int e) {
    return e == 0 ? v.x : e == 1 ? v.y : e == 2 ? v.z : v.w;
}

// prep: w2 -> bf16 (blocks 0..195), w1 -> transposed fp32 w1t[c][o] (blocks 196..211)
__global__ __launch_bounds__(256) void kprep(const float* __restrict__ w2,
                                             unsigned short* __restrict__ w2b,
                                             const float* __restrict__ w1,
                                             float* __restrict__ w1t) {
    int bid = blockIdx.x;
    if (bid < 196) {
        int i = (bid * 256 + threadIdx.x) * 4;
        float4 v = *(const float4*)(w2 + i);
        ushort4 r;
        r.x = f2bf(v.x); r.y = f2bf(v.y); r.z = f2bf(v.z); r.w = f2bf(v.w);
        *(ushort4*)(w2b + i) = r;
    } else {
        int L = (bid - 196) * 256 + threadIdx.x;   // 0..4095
        int c = L >> 4;
        int o4 = (L & 15) * 4;
        float4 r = make_float4(w1[(o4 + 0) * 256 + c], w1[(o4 + 1) * 256 + c],
                               w1[(o4 + 2) * 256 + c], w1[(o4 + 3) * 256 + c]);
        *(float4*)(w1t + c * 64 + o4) = r;
    }
}

// y = relu(bn(w1 @ x + b1)) bf16, ytb[pixel][64]. No LDS, streaming, 392 blocks.
__global__ __launch_bounds__(256) void ky(
    const float* __restrict__ x, const float* __restrict__ w1t,
    const float* __restrict__ b1, const float* __restrict__ gamma,
    const float* __restrict__ beta, const float* __restrict__ mean,
    const float* __restrict__ var, unsigned short* __restrict__ ytb)
{
    const int t = threadIdx.x;
    const int q = t & 7;          // pixel quad 0..7  (32 px/block)
    const int oq = t >> 3;        // 0..31
    const int o0 = oq * 2;
    const int P0 = blockIdx.x * 32;
    const int b = P0 / HW;        // 98 blocks per batch, no straddle
    const int p = P0 - b * HW + q * 4;
    const float* xp = x + (size_t)b * 256 * HW + p;

    float a00 = 0.f, a01 = 0.f, a10 = 0.f, a11 = 0.f;
    float a20 = 0.f, a21 = 0.f, a30 = 0.f, a31 = 0.f;
#pragma unroll 8
    for (int c = 0; c < 256; ++c) {
        float4 xv = *(const float4*)(xp + (size_t)c * HW);
        float2 wv = *(const float2*)(w1t + c * 64 + o0);
        a00 += xv.x * wv.x; a01 += xv.x * wv.y;
        a10 += xv.y * wv.x; a11 += xv.y * wv.y;
        a20 += xv.z * wv.x; a21 += xv.z * wv.y;
        a30 += xv.w * wv.x; a31 += xv.w * wv.y;
    }
    float sc0 = gamma[o0] * rsqrtf(var[o0] + 1e-5f);
    float sh0 = beta[o0] - mean[o0] * sc0 + b1[o0] * sc0;
    float sc1 = gamma[o0 + 1] * rsqrtf(var[o0 + 1] + 1e-5f);
    float sh1 = beta[o0 + 1] - mean[o0 + 1] * sc1 + b1[o0 + 1] * sc1;
    float r0[4] = {a00, a10, a20, a30}, r1[4] = {a01, a11, a21, a31};
#pragma unroll
    for (int i = 0; i < 4; ++i) {
        ushort2 r;
        r.x = f2bf(fmaxf(r0[i] * sc0 + sh0, 0.f));
        r.y = f2bf(fmaxf(r1[i] * sc1 + sh1, 0.f));
        *(ushort2*)(ytb + (size_t)(P0 + q * 4 + i) * 64 + o0) = r;
    }
}

// Fused weight-gen (bf16 MFMA) + involution. 3 blocks/CU (52.3 KB LDS).
__global__ __launch_bounds__(256, 3) void kmain(
    const float* __restrict__ x, const unsigned short* __restrict__ w2b,
    const float* __restrict__ b2, const unsigned short* __restrict__ ytb,
    float* __restrict__ out)
{
    __shared__ unsigned short wgt[16 * WSTR];  // [pix][g][52] bf16, 26752 B
    __shared__ float4 xs4[16 * 100];           // [g][r][c] 10x10 f4,  25600 B
    const int t = threadIdx.x;
    const int pix = t & 15, sub = t >> 4;
    const int lane = t & 63, wave = t >> 6;
    const int b = blockIdx.z, h0 = blockIdx.y * 4, w0 = blockIdx.x * 4;
    const int ph = pix >> 2, pw = pix & 3;
    const int h = h0 + ph, w = w0 + pw;

    // B-fragments: the tile's 16 y-vectors (same in all 4 waves)
    const int n = lane & 15, quad = lane >> 4;
    const int Pn = b * HW + (h0 + (n >> 2)) * 56 + w0 + (n & 3);
    const short8 bf0 = *(const short8*)(ytb + (size_t)Pn * 64 + quad * 8);
    const short8 bf1 = *(const short8*)(ytb + (size_t)Pn * 64 + quad * 8 + 32);

    // zero the 3 pad taps per (pix, group) once; never rewritten
    for (int i = t; i < 768; i += 256) {
        int p = i / 48, rem = i - p * 48;
        int g = rem / 3, kk = 49 + (rem - g * 3);
        wgt[p * WSTR + g * 52 + kk] = 0;
    }

    const int sg = t & 15, sr = t >> 4;   // staging job: group, row (t<160)

    for (int chunk = 0; chunk < 4; ++chunk) {
        if (chunk) __syncthreads();       // prev involution done with xs+wgt

        // ---- stage x footprint: 64 ch, rows h0-3..h0+6, cols w0-3..w0+6
        if (t < 160) {
            int hh = h0 + sr - 3;
            float4 rv[4][3];
            if (hh >= 0 && hh < 56) {
                const float* src = x + ((size_t)b * 256 + (chunk << 6) + sg * 4) * HW + hh * 56;
#pragma unroll
                for (int qq = 0; qq < 3; ++qq) {
                    int col0 = w0 - 4 + qq * 4;
                    if (col0 >= 0 && col0 + 3 <= 55) {
#pragma unroll
                        for (int ci = 0; ci < 4; ++ci)
                            rv[ci][qq] = *(const float4*)(src + ci * HW + col0);
                    } else {
#pragma unroll
                        for (int ci = 0; ci < 4; ++ci) {
                            float tmp[4];
#pragma unroll
                            for (int e = 0; e < 4; ++e) {
                                int col = col0 + e;
                                tmp[e] = (col >= 0 && col <= 55) ? src[ci * HW + col] : 0.f;
                            }
                            rv[ci][qq] = make_float4(tmp[0], tmp[1], tmp[2], tmp[3]);
                        }
                    }
                }
            } else {
#pragma unroll
                for (int qq = 0; qq < 3; ++qq)
#pragma unroll
                    for (int ci = 0; ci < 4; ++ci)
                        rv[ci][qq] = make_float4(0.f, 0.f, 0.f, 0.f);
            }
            float4* dst = &xs4[sg * 100 + sr * 10];
#pragma unroll
            for (int s = 0; s < 10; ++s) {
                int qq = (s + 1) >> 2, e = (s + 1) & 3;
                dst[s] = make_float4(fget(rv[0][qq], e), fget(rv[1][qq], e),
                                     fget(rv[2][qq], e), fget(rv[3][qq], e));
            }
        }

        // ---- weight generation: 784 chl x 16 px via MFMA (A from L2)
        const int c0 = chunk * 784;
        for (int tile = wave; tile < 49; tile += 4) {
            const unsigned short* ap = w2b + (size_t)(c0 + tile * 16 + n) * 64 + quad * 8;
            short8 af0 = *(const short8*)(ap);
            short8 af1 = *(const short8*)(ap + 32);
            f32x4 acc = {0.f, 0.f, 0.f, 0.f};
            acc = __builtin_amdgcn_mfma_f32_16x16x32_bf16(af0, bf0, acc, 0, 0, 0);
            acc = __builtin_amdgcn_mfma_f32_16x16x32_bf16(af1, bf1, acc, 0, 0, 0);
            int rbase = tile * 16 + quad * 4;
#pragma unroll
            for (int r = 0; r < 4; ++r) {
                int chl = rbase + r;
                int g = chl / 49;            // magic-mul const div
                int kk = chl - g * 49;
                float wv = acc[r] + b2[c0 + chl];
                wgt[n * WSTR + g * 52 + kk] = f2bf(wv);
            }
        }
        __syncthreads();                    // xs + wgt ready

        // ---- involution: thread = (group sub, 4 channels, pixel pix)
        const unsigned short* wr = &wgt[pix * WSTR + sub * 52];
        const float4* xr = &xs4[sub * 100];
        float a0 = 0.f, a1 = 0.f, a2 = 0.f, a3 = 0.f;
#pragma unroll
        for (int kq = 0; kq < 13; ++kq) {
            uint2 wp = *(const uint2*)(wr + kq * 4);
#pragma unroll
            for (int e = 0; e < 4; ++e) {
                int k = kq * 4 + e;
                if (k < 49) {
                    int ki = k / 7, kj = k - ki * 7;       // compile-time
                    unsigned int uw = (e < 2) ? wp.x : wp.y;
                    unsigned int ub = (e & 1) ? (uw & 0xffff0000u) : (uw << 16);
                    float wv = __uint_as_float(ub);
                    float4 xv = xr[(ph + ki) * 10 + (pw + kj)];
                    a0 += wv * xv.x; a1 += wv * xv.y;
                    a2 += wv * xv.z; a3 += wv * xv.w;
                }
            }
        }
        size_t ob = ((size_t)b * 256 + chunk * 64 + sub * 4) * HW + h * 56 + w;
        out[ob] = a0;
        out[ob + HW] = a1;
        out[ob + 2 * HW] = a2;
        out[ob + 3 * HW] = a3;
    }
}

extern "C" void kernel_launch(void* const* d_in, const int* in_sizes, int n_in,
                              void* d_out, int out_size, void* d_ws, size_t ws_size,
                              hipStream_t stream) {
    const float* x     = (const float*)d_in[0];
    const float* w1    = (const float*)d_in[1];
    const float* b1    = (const float*)d_in[2];
    const float* gamma = (const float*)d_in[3];
    const float* beta  = (const float*)d_in[4];
    const float* mean  = (const float*)d_in[5];
    const float* var   = (const float*)d_in[6];
    const float* w2    = (const float*)d_in[7];
    const float* b2    = (const float*)d_in[8];
    float* out = (float*)d_out;

    unsigned short* ytb = (unsigned short*)d_ws;           // 802816 ushorts
    unsigned short* w2b = ytb + (size_t)NPX * 64;          // 200704 ushorts
    float* w1t = (float*)(w2b + 200704);                   // 16384 floats

    hipLaunchKernelGGL(kprep, dim3(212), dim3(256), 0, stream, w2, w2b, w1, w1t);
    hipLaunchKernelGGL(ky, dim3(392), dim3(256), 0, stream,
                       x, w1t, b1, gamma, beta, mean, var, ytb);
    hipLaunchKernelGGL(kmain, dim3(14, 14, 4), dim3(256), 0, stream,
                       x, w2b, b2, ytb, out);
}

// Round 4
// 173.947 us; speedup vs baseline: 1.1575x; 1.1575x over previous
//
#include <hip/hip_runtime.h>

typedef short short8 __attribute__((ext_vector_type(8)));
typedef float f32x4 __attribute__((ext_vector_type(4)));

#define HW 3136    // 56*56
#define NPX 12544  // B*HW
#define WSTR 844   // wgt pixel stride (ushorts): 16 groups * 52 + pad, 8B-aligned, 422dw%32=6
#define YSTR 96    // ytb row stride (K extended: 64 y + [1, 0..0] for b2)

__device__ __forceinline__ unsigned short f2bf(float f) {
    union { float f; unsigned int u; } v; v.f = f;
    unsigned int u = v.u;
    u += 0x7FFFu + ((u >> 16) & 1u);
    return (unsigned short)(u >> 16);
}

__device__ __forceinline__ float fget(const float4& v, int e) {
    return e == 0 ? v.x : e == 1 ? v.y : e == 2 ? v.z : v.w;
}

// prep: w2b96[ch][96] = bf16([w2 | b2 | 0..]), w1b = bf16(w1) [64][256], scsh[64] = (sc, sh)
__global__ __launch_bounds__(256) void kprep(
    const float* __restrict__ w2, const float* __restrict__ b2,
    const float* __restrict__ w1, const float* __restrict__ b1,
    const float* __restrict__ gamma, const float* __restrict__ beta,
    const float* __restrict__ mean, const float* __restrict__ var,
    unsigned short* __restrict__ w2b96, unsigned short* __restrict__ w1b,
    float* __restrict__ scsh)
{
    const int t = threadIdx.x, bid = blockIdx.x;
    if (bid < 196) {
        const int ch0 = bid * 16;
#pragma unroll
        for (int i = 0; i < 6; ++i) {
            int j = i * 256 + t;               // 1536 = 16 ch * 96
            int ch = ch0 + j / 96, col = j - (j / 96) * 96;
            float v = col < 64 ? w2[ch * 64 + col] : (col == 64 ? b2[ch] : 0.f);
            w2b96[ch * 96 + col] = f2bf(v);
        }
    } else {
        for (int i = 0; i < 64; ++i) {
            int j = i * 256 + t;               // 16384
            w1b[j] = f2bf(w1[j]);
        }
        if (t < 64) {
            float sc = gamma[t] * rsqrtf(var[t] + 1e-5f);
            float sh = beta[t] - mean[t] * sc + b1[t] * sc;
            scsh[t * 2] = sc;
            scsh[t * 2 + 1] = sh;
        }
    }
}

// y-GEMM via MFMA: y = relu(bn(w1 @ x)), bf16 -> ytb[px][96] (col64=1, rest 0)
__global__ __launch_bounds__(256) void ky2(
    const float* __restrict__ x, const unsigned short* __restrict__ w1b,
    const float* __restrict__ scsh, unsigned short* __restrict__ ytb)
{
    __shared__ unsigned short xt[16 * 264];    // [px][ch], stride 264
    const int t = threadIdx.x;
    const int px0 = blockIdx.x * 16;
    const int b = px0 / HW;
    const int p0 = px0 - b * HW;

    // stage x tile: 16 px x 256 ch fp32 -> bf16 LDS (transposed to [px][ch])
#pragma unroll
    for (int i = 0; i < 4; ++i) {
        int j = i * 256 + t;                   // 1024 jobs: (c, pixel-quad)
        int c = j >> 2, pq = j & 3;
        float4 v = *(const float4*)(x + (size_t)(b * 256 + c) * HW + p0 + pq * 4);
        xt[(pq * 4 + 0) * 264 + c] = f2bf(v.x);
        xt[(pq * 4 + 1) * 264 + c] = f2bf(v.y);
        xt[(pq * 4 + 2) * 264 + c] = f2bf(v.z);
        xt[(pq * 4 + 3) * 264 + c] = f2bf(v.w);
    }
    // constant tail of ytb rows: [64]=1.0bf16, [65..95]=0
    if (t < 16) {
        unsigned short* yr = ytb + (size_t)(px0 + t) * YSTR + 64;
        ushort4 one = {0x3F80u, 0, 0, 0}, z = {0, 0, 0, 0};
        *(ushort4*)(yr) = one;
#pragma unroll
        for (int q = 1; q < 8; ++q) *(ushort4*)(yr + q * 4) = z;
    }
    __syncthreads();

    const int lane = t & 63, wave = t >> 6;
    const int n = lane & 15, quad = lane >> 4;
    const int m0 = wave * 16;

    f32x4 acc = {0.f, 0.f, 0.f, 0.f};
#pragma unroll
    for (int k = 0; k < 8; ++k) {
        short8 af = *(const short8*)(w1b + (m0 + n) * 256 + k * 32 + quad * 8);
        short8 bf = *(const short8*)(&xt[n * 264 + k * 32 + quad * 8]);
        acc = __builtin_amdgcn_mfma_f32_16x16x32_bf16(af, bf, acc, 0, 0, 0);
    }
    ushort4 pack;
    unsigned short pk[4];
#pragma unroll
    for (int r = 0; r < 4; ++r) {
        int m = m0 + quad * 4 + r;
        float2 ss = *(const float2*)(scsh + m * 2);
        pk[r] = f2bf(fmaxf(acc[r] * ss.x + ss.y, 0.f));
    }
    pack.x = pk[0]; pack.y = pk[1]; pack.z = pk[2]; pack.w = pk[3];
    *(ushort4*)(ytb + (size_t)(px0 + n) * YSTR + m0 + quad * 4) = pack;
}

// Fused weight-gen (K=96 bf16 MFMA, b2 baked) + involution.
__global__ __launch_bounds__(256, 3) void kmain(
    const float* __restrict__ x, const unsigned short* __restrict__ w2b96,
    const unsigned short* __restrict__ ytb, float* __restrict__ out)
{
    __shared__ unsigned short wgt[16 * WSTR];  // [px][g][52] bf16, 27008 B
    __shared__ float4 xs4[16 * 101];           // [g][10x10 px] f4, stride 101, 25856 B
    const int t = threadIdx.x;
    const int pix = t & 15, sub = t >> 4;
    const int lane = t & 63, wave = t >> 6;
    const int b = blockIdx.z, h0 = blockIdx.y * 4, w0 = blockIdx.x * 4;
    const int ph = pix >> 2, pw = pix & 3;
    const int h = h0 + ph, w = w0 + pw;

    // B-fragments: tile's 16 y-vectors (K=96: includes the b2 lane)
    const int n = lane & 15, quad = lane >> 4;
    const int Pn = b * HW + (h0 + (n >> 2)) * 56 + w0 + (n & 3);
    const unsigned short* yr = ytb + (size_t)Pn * YSTR + quad * 8;
    const short8 bf0 = *(const short8*)(yr);
    const short8 bf1 = *(const short8*)(yr + 32);
    const short8 bf2 = *(const short8*)(yr + 64);

    // zero wgt pad taps (k=49..51) once
    for (int i = t; i < 768; i += 256) {
        int p = i / 48, rem = i - p * 48;
        int g = rem / 3, kk = 49 + (rem - g * 3);
        wgt[p * WSTR + g * 52 + kk] = 0;
    }

    const int sg = t & 15, sr = t >> 4;   // staging job: group, row (t<160)

    for (int chunk = 0; chunk < 4; ++chunk) {
        if (chunk) __syncthreads();

        // ---- stage x footprint: 64 ch, rows h0-3..h0+6, cols w0-3..w0+6
        if (t < 160) {
            int hh = h0 + sr - 3;
            float4 rv[4][3];
            if (hh >= 0 && hh < 56) {
                const float* src = x + ((size_t)b * 256 + (chunk << 6) + sg * 4) * HW + hh * 56;
#pragma unroll
                for (int qq = 0; qq < 3; ++qq) {
                    int col0 = w0 - 4 + qq * 4;
                    if (col0 >= 0 && col0 + 3 <= 55) {
#pragma unroll
                        for (int ci = 0; ci < 4; ++ci)
                            rv[ci][qq] = *(const float4*)(src + ci * HW + col0);
                    } else {
#pragma unroll
                        for (int ci = 0; ci < 4; ++ci) {
                            float tmp[4];
#pragma unroll
                            for (int e = 0; e < 4; ++e) {
                                int col = col0 + e;
                                tmp[e] = (col >= 0 && col <= 55) ? src[ci * HW + col] : 0.f;
                            }
                            rv[ci][qq] = make_float4(tmp[0], tmp[1], tmp[2], tmp[3]);
                        }
                    }
                }
            } else {
#pragma unroll
                for (int qq = 0; qq < 3; ++qq)
#pragma unroll
                    for (int ci = 0; ci < 4; ++ci)
                        rv[ci][qq] = make_float4(0.f, 0.f, 0.f, 0.f);
            }
            float4* dst = &xs4[sg * 101 + sr * 10];
#pragma unroll
            for (int s = 0; s < 10; ++s) {
                int qq = (s + 1) >> 2, e = (s + 1) & 3;
                dst[s] = make_float4(fget(rv[0][qq], e), fget(rv[1][qq], e),
                                     fget(rv[2][qq], e), fget(rv[3][qq], e));
            }
        }

        // ---- weight generation: 784 ch x 16 px, K=96 MFMA (b2 baked in)
        const int c0 = chunk * 784;
        for (int tile = wave; tile < 49; tile += 4) {
            const unsigned short* ap = w2b96 + (size_t)(c0 + tile * 16 + n) * 96 + quad * 8;
            short8 af0 = *(const short8*)(ap);
            short8 af1 = *(const short8*)(ap + 32);
            short8 af2 = *(const short8*)(ap + 64);
            f32x4 acc = {0.f, 0.f, 0.f, 0.f};
            acc = __builtin_amdgcn_mfma_f32_16x16x32_bf16(af0, bf0, acc, 0, 0, 0);
            acc = __builtin_amdgcn_mfma_f32_16x16x32_bf16(af1, bf1, acc, 0, 0, 0);
            acc = __builtin_amdgcn_mfma_f32_16x16x32_bf16(af2, bf2, acc, 0, 0, 0);
            int rbase = tile * 16 + quad * 4;
#pragma unroll
            for (int r = 0; r < 4; ++r) {
                int chl = rbase + r;
                int g = chl / 49;
                int kk = chl - g * 49;
                wgt[n * WSTR + g * 52 + kk] = f2bf(acc[r]);
            }
        }
        __syncthreads();

        // ---- involution: thread = (group sub, 4 channels, pixel pix)
        const unsigned short* wr = &wgt[pix * WSTR + sub * 52];
        const float4* xr = &xs4[sub * 101];
        float a0 = 0.f, a1 = 0.f, a2 = 0.f, a3 = 0.f;
#pragma unroll
        for (int kq = 0; kq < 13; ++kq) {
            uint2 wp = *(const uint2*)(wr + kq * 4);
#pragma unroll
            for (int e = 0; e < 4; ++e) {
                int k = kq * 4 + e;
                if (k < 49) {
                    int ki = k / 7, kj = k - ki * 7;       // compile-time
                    unsigned int uw = (e < 2) ? wp.x : wp.y;
                    unsigned int ub = (e & 1) ? (uw & 0xffff0000u) : (uw << 16);
                    float wv = __uint_as_float(ub);
                    float4 xv = xr[(ph + ki) * 10 + (pw + kj)];
                    a0 += wv * xv.x; a1 += wv * xv.y;
                    a2 += wv * xv.z; a3 += wv * xv.w;
                }
            }
        }
        size_t ob = ((size_t)b * 256 + chunk * 64 + sub * 4) * HW + h * 56 + w;
        out[ob] = a0;
        out[ob + HW] = a1;
        out[ob + 2 * HW] = a2;
        out[ob + 3 * HW] = a3;
    }
}

extern "C" void kernel_launch(void* const* d_in, const int* in_sizes, int n_in,
                              void* d_out, int out_size, void* d_ws, size_t ws_size,
                              hipStream_t stream) {
    const float* x     = (const float*)d_in[0];
    const float* w1    = (const float*)d_in[1];
    const float* b1    = (const float*)d_in[2];
    const float* gamma = (const float*)d_in[3];
    const float* beta  = (const float*)d_in[4];
    const float* mean  = (const float*)d_in[5];
    const float* var   = (const float*)d_in[6];
    const float* w2    = (const float*)d_in[7];
    const float* b2    = (const float*)d_in[8];
    float* out = (float*)d_out;

    unsigned short* ytb   = (unsigned short*)d_ws;         // 12544*96 = 1204224 ush
    unsigned short* w2b96 = ytb + (size_t)NPX * YSTR;      // 3136*96  = 301056 ush
    unsigned short* w1b   = w2b96 + 3136 * 96;             // 16384 ush
    float* scsh = (float*)(w1b + 16384);                   // 128 floats

    hipLaunchKernelGGL(kprep, dim3(197), dim3(256), 0, stream,
                       w2, b2, w1, b1, gamma, beta, mean, var, w2b96, w1b, scsh);
    hipLaunchKernelGGL(ky2, dim3(784), dim3(256), 0, stream, x, w1b, scsh, ytb);
    hipLaunchKernelGGL(kmain, dim3(14, 14, 4), dim3(256), 0, stream,
                       x, w2b96, ytb, out);
}

// Round 5
// 169.301 us; speedup vs baseline: 1.1892x; 1.0274x over previous
//
#include <hip/hip_runtime.h>

typedef short short8 __attribute__((ext_vector_type(8)));
typedef float f32x4 __attribute__((ext_vector_type(4)));

#define HW 3136    // 56*56
#define WSTR 844   // wgt pixel stride (ushorts): 16*52 + 12 pad; 422 dw % 32 = 6
#define XS_OFF 25856  // bytes of xs4 region: 16*101*16

__device__ __forceinline__ unsigned short f2bf(float f) {
    union { float f; unsigned int u; } v; v.f = f;
    unsigned int u = v.u;
    u += 0x7FFFu + ((u >> 16) & 1u);
    return (unsigned short)(u >> 16);
}

__device__ __forceinline__ float fget(const float4& v, int e) {
    return e == 0 ? v.x : e == 1 ? v.y : e == 2 ? v.z : v.w;
}

// x-footprint loads for one chunk into registers (no LDS side effects)
__device__ __forceinline__ void loadx(const float* __restrict__ x, int b, int chunk,
                                      int sg, int sr, int h0, int w0, float4 rv[4][3]) {
    int hh = h0 + sr - 3;
    if (hh >= 0 && hh < 56) {
        const float* src = x + ((size_t)b * 256 + (chunk << 6) + sg * 4) * HW + hh * 56;
#pragma unroll
        for (int qq = 0; qq < 3; ++qq) {
            int col0 = w0 - 4 + qq * 4;
            if (col0 >= 0 && col0 + 3 <= 55) {
#pragma unroll
                for (int ci = 0; ci < 4; ++ci)
                    rv[ci][qq] = *(const float4*)(src + ci * HW + col0);
            } else {
#pragma unroll
                for (int ci = 0; ci < 4; ++ci) {
                    float tmp[4];
#pragma unroll
                    for (int e = 0; e < 4; ++e) {
                        int col = col0 + e;
                        tmp[e] = (col >= 0 && col <= 55) ? src[ci * HW + col] : 0.f;
                    }
                    rv[ci][qq] = make_float4(tmp[0], tmp[1], tmp[2], tmp[3]);
                }
            }
        }
    } else {
#pragma unroll
        for (int qq = 0; qq < 3; ++qq)
#pragma unroll
            for (int ci = 0; ci < 4; ++ci)
                rv[ci][qq] = make_float4(0.f, 0.f, 0.f, 0.f);
    }
}

// prep: w2b96[ch][96] = bf16([w2 | b2 | 0..]); w1b = bf16(w1) [64][256]; scsh[64]=(sc,sh)
__global__ __launch_bounds__(256) void kprep(
    const float* __restrict__ w2, const float* __restrict__ b2,
    const float* __restrict__ w1, const float* __restrict__ b1,
    const float* __restrict__ gamma, const float* __restrict__ beta,
    const float* __restrict__ mean, const float* __restrict__ var,
    unsigned short* __restrict__ w2b96, unsigned short* __restrict__ w1b,
    float* __restrict__ scsh)
{
    const int t = threadIdx.x, bid = blockIdx.x;
    if (bid < 196) {
        const int ch0 = bid * 16;
#pragma unroll
        for (int i = 0; i < 6; ++i) {
            int j = i * 256 + t;               // 1536 = 16 ch * 96
            int ch = ch0 + j / 96, col = j - (j / 96) * 96;
            float v = col < 64 ? w2[ch * 64 + col] : (col == 64 ? b2[ch] : 0.f);
            w2b96[ch * 96 + col] = f2bf(v);
        }
    } else if (bid < 212) {
        int j = (bid - 196) * 1024 + t * 4;    // 16 blocks x 1024
        float4 v = *(const float4*)(w1 + j);
        ushort4 r;
        r.x = f2bf(v.x); r.y = f2bf(v.y); r.z = f2bf(v.z); r.w = f2bf(v.w);
        *(ushort4*)(w1b + j) = r;
    } else if (t < 64) {
        float sc = gamma[t] * rsqrtf(var[t] + 1e-5f);
        float sh = beta[t] - mean[t] * sc + b1[t] * sc;
        scsh[t * 2] = sc;
        scsh[t * 2 + 1] = sh;
    }
}

// Fully fused: y-GEMM (in-block) + weight-gen (K=96 MFMA) + involution.
__global__ __launch_bounds__(256, 3) void kmain(
    const float* __restrict__ x, const unsigned short* __restrict__ w2b96,
    const unsigned short* __restrict__ w1b, const float* __restrict__ scsh,
    float* __restrict__ out)
{
    __shared__ __align__(16) char smem[52864];
    float4* xs4 = (float4*)smem;                           // 16*101 f4 = 25856 B
    unsigned short* wgt = (unsigned short*)(smem + XS_OFF);// 16*844 ush = 27008 B
    unsigned short* ys = (unsigned short*)smem;            // alias: 16*96 ush = 3072 B
    unsigned short* xt = (unsigned short*)(smem + XS_OFF); // alias: 16*264 ush = 8448 B

    const int t = threadIdx.x;
    const int pix = t & 15, sub = t >> 4;
    const int lane = t & 63, wave = t >> 6;
    const int b = blockIdx.z, h0 = blockIdx.y * 4, w0 = blockIdx.x * 4;
    const int ph = pix >> 2, pw = pix & 3;
    const int h = h0 + ph, w = w0 + pw;
    const int n = lane & 15, quad = lane >> 4;
    const int sg = t & 15, sr = t >> 4;       // staging job (t<160)

    // prefetch chunk-0 x footprint immediately (hidden behind y-GEMM)
    float4 rv[4][3];
    if (t < 160) loadx(x, b, 0, sg, sr, h0, w0, rv);

    // ---- stage x tile for y-GEMM: 16 px x 256 ch -> bf16 xt[px][264]
#pragma unroll
    for (int i = 0; i < 4; ++i) {
        int j = i * 256 + t;                  // (c, tile-row)
        int c = j >> 2, r = j & 3;
        float4 v = *(const float4*)(x + ((size_t)b * 256 + c) * HW + (h0 + r) * 56 + w0);
        xt[(r * 4 + 0) * 264 + c] = f2bf(v.x);
        xt[(r * 4 + 1) * 264 + c] = f2bf(v.y);
        xt[(r * 4 + 2) * 264 + c] = f2bf(v.z);
        xt[(r * 4 + 3) * 264 + c] = f2bf(v.w);
    }
    __syncthreads();

    // ---- y-GEMM: wave computes y-channels wave*16..+15 for all 16 px
    {
        const int m0 = wave * 16;
        f32x4 yacc = {0.f, 0.f, 0.f, 0.f};
#pragma unroll
        for (int k = 0; k < 8; ++k) {
            short8 af = *(const short8*)(w1b + (m0 + n) * 256 + k * 32 + quad * 8);
            short8 bfx = *(const short8*)(xt + n * 264 + k * 32 + quad * 8);
            yacc = __builtin_amdgcn_mfma_f32_16x16x32_bf16(af, bfx, yacc, 0, 0, 0);
        }
        ushort4 pack;
        unsigned short pk[4];
#pragma unroll
        for (int r = 0; r < 4; ++r) {
            int m = m0 + quad * 4 + r;
            float2 ss = *(const float2*)(scsh + m * 2);
            pk[r] = f2bf(fmaxf(yacc[r] * ss.x + ss.y, 0.f));
        }
        pack.x = pk[0]; pack.y = pk[1]; pack.z = pk[2]; pack.w = pk[3];
        *(ushort4*)(ys + n * 96 + m0 + quad * 4) = pack;
    }
    if (t < 16) {        // K-extension tail: col64 = 1.0 (b2 lane), 65..95 = 0
        unsigned short* yrow = ys + t * 96 + 64;
        ushort4 one; one.x = 0x3F80u; one.y = 0; one.z = 0; one.w = 0;
        ushort4 z; z.x = 0; z.y = 0; z.z = 0; z.w = 0;
        *(ushort4*)(yrow) = one;
#pragma unroll
        for (int q = 1; q < 8; ++q) *(ushort4*)(yrow + q * 4) = z;
    }
    __syncthreads();

    // ---- B-fragments for weight-gen (K=96, incl. b2 lane)
    const short8 bf0 = *(const short8*)(ys + n * 96 + quad * 8);
    const short8 bf1 = *(const short8*)(ys + n * 96 + quad * 8 + 32);
    const short8 bf2 = *(const short8*)(ys + n * 96 + quad * 8 + 64);

    // zero wgt pad taps (k=49..51); xt region now dead
    for (int i = t; i < 768; i += 256) {
        int p = i / 48, rem = i - p * 48;
        int g = rem / 3, kk = 49 + (rem - g * 3);
        wgt[p * WSTR + g * 52 + kk] = 0;
    }
    __syncthreads();     // ys reads done before xs4 staging overwrites

    for (int chunk = 0; chunk < 4; ++chunk) {
        if (chunk) __syncthreads();

        // ---- commit prefetched x footprint to LDS
        if (t < 160) {
            float4* dst = &xs4[sg * 101 + sr * 10];
#pragma unroll
            for (int s = 0; s < 10; ++s) {
                int qq = (s + 1) >> 2, e = (s + 1) & 3;
                dst[s] = make_float4(fget(rv[0][qq], e), fget(rv[1][qq], e),
                                     fget(rv[2][qq], e), fget(rv[3][qq], e));
            }
        }

        // ---- weight generation: 784 ch x 16 px, K=96 MFMA (b2 baked)
        const int c0 = chunk * 784;
        for (int tile = wave; tile < 49; tile += 4) {
            const unsigned short* ap = w2b96 + (size_t)(c0 + tile * 16 + n) * 96 + quad * 8;
            short8 af0 = *(const short8*)(ap);
            short8 af1 = *(const short8*)(ap + 32);
            short8 af2 = *(const short8*)(ap + 64);
            f32x4 acc = {0.f, 0.f, 0.f, 0.f};
            acc = __builtin_amdgcn_mfma_f32_16x16x32_bf16(af0, bf0, acc, 0, 0, 0);
            acc = __builtin_amdgcn_mfma_f32_16x16x32_bf16(af1, bf1, acc, 0, 0, 0);
            acc = __builtin_amdgcn_mfma_f32_16x16x32_bf16(af2, bf2, acc, 0, 0, 0);
            int rbase = tile * 16 + quad * 4;
#pragma unroll
            for (int r = 0; r < 4; ++r) {
                int chl = rbase + r;
                int g = chl / 49;
                int kk = chl - g * 49;
                wgt[n * WSTR + g * 52 + kk] = f2bf(acc[r]);
            }
        }
        __syncthreads();

        // ---- prefetch next chunk's x during involution
        if (chunk < 3 && t < 160) loadx(x, b, chunk + 1, sg, sr, h0, w0, rv);

        // ---- involution: thread = (group sub, 4 channels, pixel pix)
        const unsigned short* wr = &wgt[pix * WSTR + sub * 52];
        const float4* xr = &xs4[sub * 101];
        float a0 = 0.f, a1 = 0.f, a2 = 0.f, a3 = 0.f;
#pragma unroll
        for (int kq = 0; kq < 13; ++kq) {
            uint2 wp = *(const uint2*)(wr + kq * 4);
#pragma unroll
            for (int e = 0; e < 4; ++e) {
                int k = kq * 4 + e;
                if (k < 49) {
                    unsigned int uw = (e < 2) ? wp.x : wp.y;
                    unsigned int ub = (e & 1) ? (uw & 0xffff0000u) : (uw << 16);
                    float wv = __uint_as_float(ub);
                    int ki = k / 7, kj = k - ki * 7;       // compile-time
                    float4 xv = xr[(ph + ki) * 10 + (pw + kj)];
                    a0 += wv * xv.x; a1 += wv * xv.y;
                    a2 += wv * xv.z; a3 += wv * xv.w;
                }
            }
        }
        size_t ob = ((size_t)b * 256 + chunk * 64 + sub * 4) * HW + h * 56 + w;
        out[ob] = a0;
        out[ob + HW] = a1;
        out[ob + 2 * HW] = a2;
        out[ob + 3 * HW] = a3;
    }
}

extern "C" void kernel_launch(void* const* d_in, const int* in_sizes, int n_in,
                              void* d_out, int out_size, void* d_ws, size_t ws_size,
                              hipStream_t stream) {
    const float* x     = (const float*)d_in[0];
    const float* w1    = (const float*)d_in[1];
    const float* b1    = (const float*)d_in[2];
    const float* gamma = (const float*)d_in[3];
    const float* beta  = (const float*)d_in[4];
    const float* mean  = (const float*)d_in[5];
    const float* var   = (const float*)d_in[6];
    const float* w2    = (const float*)d_in[7];
    const float* b2    = (const float*)d_in[8];
    float* out = (float*)d_out;

    unsigned short* w2b96 = (unsigned short*)d_ws;         // 3136*96 ush = 602112 B
    unsigned short* w1b   = w2b96 + 3136 * 96;             // 16384 ush
    float* scsh = (float*)(w1b + 16384);                   // 128 floats

    hipLaunchKernelGGL(kprep, dim3(213), dim3(256), 0, stream,
                       w2, b2, w1, b1, gamma, beta, mean, var, w2b96, w1b, scsh);
    hipLaunchKernelGGL(kmain, dim3(14, 14, 4), dim3(256), 0, stream,
                       x, w2b96, w1b, scsh, out);
}

// Round 6
// 157.656 us; speedup vs baseline: 1.2771x; 1.0739x over previous
//
#include <hip/hip_runtime.h>

typedef short short8 __attribute__((ext_vector_type(8)));
typedef float f32x4 __attribute__((ext_vector_type(4)));

#define HW 3136    // 56*56
#define WSTR 844   // wgt pixel stride (ushorts): 16*52 + 12 pad; 422 dw % 32 = 6
#define XS_OFF 12928  // bytes of xsb region: 16*101*8

__device__ __forceinline__ unsigned short f2bf(float f) {
    union { float f; unsigned int u; } v; v.f = f;
    unsigned int u = v.u;
    u += 0x7FFFu + ((u >> 16) & 1u);
    return (unsigned short)(u >> 16);
}

__device__ __forceinline__ float fget(const float4& v, int e) {
    return e == 0 ? v.x : e == 1 ? v.y : e == 2 ? v.z : v.w;
}

// x-footprint loads for one chunk into registers (no LDS side effects)
__device__ __forceinline__ void loadx(const float* __restrict__ x, int b, int chunk,
                                      int sg, int sr, int h0, int w0, float4 rv[4][3]) {
    int hh = h0 + sr - 3;
    if (hh >= 0 && hh < 56) {
        const float* src = x + ((size_t)b * 256 + (chunk << 6) + sg * 4) * HW + hh * 56;
#pragma unroll
        for (int qq = 0; qq < 3; ++qq) {
            int col0 = w0 - 4 + qq * 4;
            if (col0 >= 0 && col0 + 3 <= 55) {
#pragma unroll
                for (int ci = 0; ci < 4; ++ci)
                    rv[ci][qq] = *(const float4*)(src + ci * HW + col0);
            } else {
#pragma unroll
                for (int ci = 0; ci < 4; ++ci) {
                    float tmp[4];
#pragma unroll
                    for (int e = 0; e < 4; ++e) {
                        int col = col0 + e;
                        tmp[e] = (col >= 0 && col <= 55) ? src[ci * HW + col] : 0.f;
                    }
                    rv[ci][qq] = make_float4(tmp[0], tmp[1], tmp[2], tmp[3]);
                }
            }
        }
    } else {
#pragma unroll
        for (int qq = 0; qq < 3; ++qq)
#pragma unroll
            for (int ci = 0; ci < 4; ++ci)
                rv[ci][qq] = make_float4(0.f, 0.f, 0.f, 0.f);
    }
}

// prep: w2b96[ch][96] = bf16([w2 | b2 | 0..]); w1b = bf16(w1) [64][256]; scsh[64]=(sc,sh)
__global__ __launch_bounds__(256) void kprep(
    const float* __restrict__ w2, const float* __restrict__ b2,
    const float* __restrict__ w1, const float* __restrict__ b1,
    const float* __restrict__ gamma, const float* __restrict__ beta,
    const float* __restrict__ mean, const float* __restrict__ var,
    unsigned short* __restrict__ w2b96, unsigned short* __restrict__ w1b,
    float* __restrict__ scsh)
{
    const int t = threadIdx.x, bid = blockIdx.x;
    if (bid < 196) {
        const int ch0 = bid * 16;
#pragma unroll
        for (int i = 0; i < 6; ++i) {
            int j = i * 256 + t;               // 1536 = 16 ch * 96
            int ch = ch0 + j / 96, col = j - (j / 96) * 96;
            float v = col < 64 ? w2[ch * 64 + col] : (col == 64 ? b2[ch] : 0.f);
            w2b96[ch * 96 + col] = f2bf(v);
        }
    } else if (bid < 212) {
        int j = (bid - 196) * 1024 + t * 4;    // 16 blocks x 1024
        float4 v = *(const float4*)(w1 + j);
        ushort4 r;
        r.x = f2bf(v.x); r.y = f2bf(v.y); r.z = f2bf(v.z); r.w = f2bf(v.w);
        *(ushort4*)(w1b + j) = r;
    } else if (t < 64) {
        float sc = gamma[t] * rsqrtf(var[t] + 1e-5f);
        float sh = beta[t] - mean[t] * sc + b1[t] * sc;
        scsh[t * 2] = sc;
        scsh[t * 2 + 1] = sh;
    }
}

// Fully fused: y-GEMM (in-block) + weight-gen (K=96 MFMA, pipelined) + involution.
// LDS 39936 B -> 4 blocks/CU, grid 784 fully co-resident (no tail wave).
__global__ __launch_bounds__(256, 4) void kmain(
    const float* __restrict__ x, const unsigned short* __restrict__ w2b96,
    const unsigned short* __restrict__ w1b, const float* __restrict__ scsh,
    float* __restrict__ out)
{
    __shared__ __align__(16) char smem[39936];
    uint2* xsb = (uint2*)smem;                             // 16*101 u2 = 12928 B (bf16 x4)
    unsigned short* wgt = (unsigned short*)(smem + XS_OFF);// 16*844 ush = 27008 B
    unsigned short* ys = (unsigned short*)smem;            // alias: 16*96 ush = 3072 B
    unsigned short* xt = (unsigned short*)(smem + XS_OFF); // alias: 16*264 ush = 8448 B

    const int t = threadIdx.x;
    const int pix = t & 15, sub = t >> 4;
    const int lane = t & 63, wave = t >> 6;
    const int b = blockIdx.z, h0 = blockIdx.y * 4, w0 = blockIdx.x * 4;
    const int ph = pix >> 2, pw = pix & 3;
    const int h = h0 + ph, w = w0 + pw;
    const int n = lane & 15, quad = lane >> 4;
    const int sg = t & 15, sr = t >> 4;       // staging job (t<160)

    // prefetch chunk-0 x footprint immediately (hidden behind y-GEMM)
    float4 rv[4][3];
    if (t < 160) loadx(x, b, 0, sg, sr, h0, w0, rv);

    // ---- stage x tile for y-GEMM: 16 px x 256 ch -> bf16 xt[px][264]
#pragma unroll
    for (int i = 0; i < 4; ++i) {
        int j = i * 256 + t;                  // (c, tile-row)
        int c = j >> 2, r = j & 3;
        float4 v = *(const float4*)(x + ((size_t)b * 256 + c) * HW + (h0 + r) * 56 + w0);
        xt[(r * 4 + 0) * 264 + c] = f2bf(v.x);
        xt[(r * 4 + 1) * 264 + c] = f2bf(v.y);
        xt[(r * 4 + 2) * 264 + c] = f2bf(v.z);
        xt[(r * 4 + 3) * 264 + c] = f2bf(v.w);
    }
    __syncthreads();

    // ---- y-GEMM: wave computes y-channels wave*16..+15 for all 16 px
    {
        const int m0 = wave * 16;
        f32x4 yacc = {0.f, 0.f, 0.f, 0.f};
#pragma unroll
        for (int k = 0; k < 8; ++k) {
            short8 af = *(const short8*)(w1b + (m0 + n) * 256 + k * 32 + quad * 8);
            short8 bfx = *(const short8*)(xt + n * 264 + k * 32 + quad * 8);
            yacc = __builtin_amdgcn_mfma_f32_16x16x32_bf16(af, bfx, yacc, 0, 0, 0);
        }
        ushort4 pack;
        unsigned short pk[4];
#pragma unroll
        for (int r = 0; r < 4; ++r) {
            int m = m0 + quad * 4 + r;
            float2 ss = *(const float2*)(scsh + m * 2);
            pk[r] = f2bf(fmaxf(yacc[r] * ss.x + ss.y, 0.f));
        }
        pack.x = pk[0]; pack.y = pk[1]; pack.z = pk[2]; pack.w = pk[3];
        *(ushort4*)(ys + n * 96 + m0 + quad * 4) = pack;
    }
    if (t < 16) {        // K-extension tail: col64 = 1.0 (b2 lane), 65..95 = 0
        unsigned short* yrow = ys + t * 96 + 64;
        ushort4 one; one.x = 0x3F80u; one.y = 0; one.z = 0; one.w = 0;
        ushort4 z; z.x = 0; z.y = 0; z.z = 0; z.w = 0;
        *(ushort4*)(yrow) = one;
#pragma unroll
        for (int q = 1; q < 8; ++q) *(ushort4*)(yrow + q * 4) = z;
    }
    __syncthreads();

    // ---- B-fragments for weight-gen (K=96, incl. b2 lane)
    const short8 bf0 = *(const short8*)(ys + n * 96 + quad * 8);
    const short8 bf1 = *(const short8*)(ys + n * 96 + quad * 8 + 32);
    const short8 bf2 = *(const short8*)(ys + n * 96 + quad * 8 + 64);

    // zero wgt pad taps (k=49..51); xt region now dead
    for (int i = t; i < 768; i += 256) {
        int p = i / 48, rem = i - p * 48;
        int g = rem / 3, kk = 49 + (rem - g * 3);
        wgt[p * WSTR + g * 52 + kk] = 0;
    }
    __syncthreads();     // ys reads done before xsb staging overwrites

    for (int chunk = 0; chunk < 4; ++chunk) {
        if (chunk) __syncthreads();

        // ---- commit prefetched x footprint to LDS as packed bf16x4
        if (t < 160) {
            uint2* dst = &xsb[sg * 101 + sr * 10];
#pragma unroll
            for (int s = 0; s < 10; ++s) {
                int qq = (s + 1) >> 2, e = (s + 1) & 3;
                uint2 pkx;
                pkx.x = (unsigned int)f2bf(fget(rv[0][qq], e)) |
                        ((unsigned int)f2bf(fget(rv[1][qq], e)) << 16);
                pkx.y = (unsigned int)f2bf(fget(rv[2][qq], e)) |
                        ((unsigned int)f2bf(fget(rv[3][qq], e)) << 16);
                dst[s] = pkx;
            }
        }

        // ---- weight generation: 784 ch x 16 px, K=96 MFMA, pipelined A-loads
        const int c0 = chunk * 784;
        {
            const unsigned short* ap = w2b96 + (size_t)(c0 + wave * 16 + n) * 96 + quad * 8;
            short8 af0 = *(const short8*)(ap);
            short8 af1 = *(const short8*)(ap + 32);
            short8 af2 = *(const short8*)(ap + 64);
            for (int tile = wave; tile < 49; tile += 4) {
                short8 ca0 = af0, ca1 = af1, ca2 = af2;
                if (tile + 4 < 49) {
                    const unsigned short* ap2 =
                        w2b96 + (size_t)(c0 + (tile + 4) * 16 + n) * 96 + quad * 8;
                    af0 = *(const short8*)(ap2);
                    af1 = *(const short8*)(ap2 + 32);
                    af2 = *(const short8*)(ap2 + 64);
                }
                f32x4 acc = {0.f, 0.f, 0.f, 0.f};
                acc = __builtin_amdgcn_mfma_f32_16x16x32_bf16(ca0, bf0, acc, 0, 0, 0);
                acc = __builtin_amdgcn_mfma_f32_16x16x32_bf16(ca1, bf1, acc, 0, 0, 0);
                acc = __builtin_amdgcn_mfma_f32_16x16x32_bf16(ca2, bf2, acc, 0, 0, 0);
                int rbase = tile * 16 + quad * 4;
#pragma unroll
                for (int r = 0; r < 4; ++r) {
                    int chl = rbase + r;
                    int g = chl / 49;
                    int kk = chl - g * 49;
                    wgt[n * WSTR + g * 52 + kk] = f2bf(acc[r]);
                }
            }
        }
        __syncthreads();

        // ---- prefetch next chunk's x during involution
        if (chunk < 3 && t < 160) loadx(x, b, chunk + 1, sg, sr, h0, w0, rv);

        // ---- involution: thread = (group sub, 4 channels, pixel pix)
        const unsigned short* wr = &wgt[pix * WSTR + sub * 52];
        const uint2* xr = &xsb[sub * 101];
        float a0 = 0.f, a1 = 0.f, a2 = 0.f, a3 = 0.f;
#pragma unroll
        for (int kq = 0; kq < 13; ++kq) {
            uint2 wp = *(const uint2*)(wr + kq * 4);
#pragma unroll
            for (int e = 0; e < 4; ++e) {
                int k = kq * 4 + e;
                if (k < 49) {
                    unsigned int uw = (e < 2) ? wp.x : wp.y;
                    unsigned int ub = (e & 1) ? (uw & 0xffff0000u) : (uw << 16);
                    float wv = __uint_as_float(ub);
                    int ki = k / 7, kj = k - ki * 7;       // compile-time
                    uint2 xp = xr[(ph + ki) * 10 + (pw + kj)];
                    a0 += wv * __uint_as_float(xp.x << 16);
                    a1 += wv * __uint_as_float(xp.x & 0xffff0000u);
                    a2 += wv * __uint_as_float(xp.y << 16);
                    a3 += wv * __uint_as_float(xp.y & 0xffff0000u);
                }
            }
        }
        size_t ob = ((size_t)b * 256 + chunk * 64 + sub * 4) * HW + h * 56 + w;
        out[ob] = a0;
        out[ob + HW] = a1;
        out[ob + 2 * HW] = a2;
        out[ob + 3 * HW] = a3;
    }
}

extern "C" void kernel_launch(void* const* d_in, const int* in_sizes, int n_in,
                              void* d_out, int out_size, void* d_ws, size_t ws_size,
                              hipStream_t stream) {
    const float* x     = (const float*)d_in[0];
    const float* w1    = (const float*)d_in[1];
    const float* b1    = (const float*)d_in[2];
    const float* gamma = (const float*)d_in[3];
    const float* beta  = (const float*)d_in[4];
    const float* mean  = (const float*)d_in[5];
    const float* var   = (const float*)d_in[6];
    const float* w2    = (const float*)d_in[7];
    const float* b2    = (const float*)d_in[8];
    float* out = (float*)d_out;

    unsigned short* w2b96 = (unsigned short*)d_ws;         // 3136*96 ush = 602112 B
    unsigned short* w1b   = w2b96 + 3136 * 96;             // 16384 ush
    float* scsh = (float*)(w1b + 16384);                   // 128 floats

    hipLaunchKernelGGL(kprep, dim3(213), dim3(256), 0, stream,
                       w2, b2, w1, b1, gamma, beta, mean, var, w2b96, w1b, scsh);
    hipLaunchKernelGGL(kmain, dim3(14, 14, 4), dim3(256), 0, stream,
                       x, w2b96, w1b, scsh, out);
}

// Round 7
// 152.838 us; speedup vs baseline: 1.3174x; 1.0315x over previous
//
#include <hip/hip_runtime.h>

typedef short short8 __attribute__((ext_vector_type(8)));
typedef float f32x4 __attribute__((ext_vector_type(4)));

#define HW 3136    // 56*56
#define NPX 12544  // B*HW
#define WSTR 844   // wgt pixel stride (ushorts): 16*52 + 12 pad; 422 dw % 32 = 6
#define YSTR 96    // ytb row stride: 64 y + [1, 0..0] b2 lane
#define XS_OFF 12928  // bytes of xsb region: 16*101*8

__device__ __forceinline__ unsigned short f2bf(float f) {
    union { float f; unsigned int u; } v; v.f = f;
    unsigned int u = v.u;
    u += 0x7FFFu + ((u >> 16) & 1u);
    return (unsigned short)(u >> 16);
}

__device__ __forceinline__ float fget(const float4& v, int e) {
    return e == 0 ? v.x : e == 1 ? v.y : e == 2 ? v.z : v.w;
}

// x-footprint loads for one chunk into registers (no LDS side effects)
__device__ __forceinline__ void loadx(const float* __restrict__ x, int b, int chunk,
                                      int sg, int sr, int h0, int w0, float4 rv[4][3]) {
    int hh = h0 + sr - 3;
    if (hh >= 0 && hh < 56) {
        const float* src = x + ((size_t)b * 256 + (chunk << 6) + sg * 4) * HW + hh * 56;
#pragma unroll
        for (int qq = 0; qq < 3; ++qq) {
            int col0 = w0 - 4 + qq * 4;
            if (col0 >= 0 && col0 + 3 <= 55) {
#pragma unroll
                for (int ci = 0; ci < 4; ++ci)
                    rv[ci][qq] = *(const float4*)(src + ci * HW + col0);
            } else {
#pragma unroll
                for (int ci = 0; ci < 4; ++ci) {
                    float tmp[4];
#pragma unroll
                    for (int e = 0; e < 4; ++e) {
                        int col = col0 + e;
                        tmp[e] = (col >= 0 && col <= 55) ? src[ci * HW + col] : 0.f;
                    }
                    rv[ci][qq] = make_float4(tmp[0], tmp[1], tmp[2], tmp[3]);
                }
            }
        }
    } else {
#pragma unroll
        for (int qq = 0; qq < 3; ++qq)
#pragma unroll
            for (int ci = 0; ci < 4; ++ci)
                rv[ci][qq] = make_float4(0.f, 0.f, 0.f, 0.f);
    }
}

// prep: w2b96[ch][96] = bf16([w2 | b2 | 0..]); w1b = bf16(w1) [64][256]; scsh[64]=(sc,sh)
__global__ __launch_bounds__(256) void kprep(
    const float* __restrict__ w2, const float* __restrict__ b2,
    const float* __restrict__ w1, const float* __restrict__ b1,
    const float* __restrict__ gamma, const float* __restrict__ beta,
    const float* __restrict__ mean, const float* __restrict__ var,
    unsigned short* __restrict__ w2b96, unsigned short* __restrict__ w1b,
    float* __restrict__ scsh)
{
    const int t = threadIdx.x, bid = blockIdx.x;
    if (bid < 196) {
        const int ch0 = bid * 16;
#pragma unroll
        for (int i = 0; i < 6; ++i) {
            int j = i * 256 + t;               // 1536 = 16 ch * 96
            int ch = ch0 + j / 96, col = j - (j / 96) * 96;
            float v = col < 64 ? w2[ch * 64 + col] : (col == 64 ? b2[ch] : 0.f);
            w2b96[ch * 96 + col] = f2bf(v);
        }
    } else if (bid < 212) {
        int j = (bid - 196) * 1024 + t * 4;    // 16 blocks x 1024
        float4 v = *(const float4*)(w1 + j);
        ushort4 r;
        r.x = f2bf(v.x); r.y = f2bf(v.y); r.z = f2bf(v.z); r.w = f2bf(v.w);
        *(ushort4*)(w1b + j) = r;
    } else if (t < 64) {
        float sc = gamma[t] * rsqrtf(var[t] + 1e-5f);
        float sh = beta[t] - mean[t] * sc + b1[t] * sc;
        scsh[t * 2] = sc;
        scsh[t * 2 + 1] = sh;
    }
}

// y-GEMM via MFMA: y = relu(bn(w1 @ x)), bf16 -> ytb[px][96] (col64=1, rest 0)
__global__ __launch_bounds__(256) void ky2(
    const float* __restrict__ x, const unsigned short* __restrict__ w1b,
    const float* __restrict__ scsh, unsigned short* __restrict__ ytb)
{
    __shared__ unsigned short xt[16 * 264];    // [px][ch], stride 264
    const int t = threadIdx.x;
    const int px0 = blockIdx.x * 16;
    const int b = px0 / HW;
    const int p0 = px0 - b * HW;

    // stage x tile: 16 px x 256 ch fp32 -> bf16 LDS (transposed to [px][ch])
#pragma unroll
    for (int i = 0; i < 4; ++i) {
        int j = i * 256 + t;                   // 1024 jobs: (c, pixel-quad)
        int c = j >> 2, pq = j & 3;
        float4 v = *(const float4*)(x + (size_t)(b * 256 + c) * HW + p0 + pq * 4);
        xt[(pq * 4 + 0) * 264 + c] = f2bf(v.x);
        xt[(pq * 4 + 1) * 264 + c] = f2bf(v.y);
        xt[(pq * 4 + 2) * 264 + c] = f2bf(v.z);
        xt[(pq * 4 + 3) * 264 + c] = f2bf(v.w);
    }
    // constant tail of ytb rows: [64]=1.0bf16, [65..95]=0
    if (t < 16) {
        unsigned short* yr = ytb + (size_t)(px0 + t) * YSTR + 64;
        ushort4 one; one.x = 0x3F80u; one.y = 0; one.z = 0; one.w = 0;
        ushort4 z; z.x = 0; z.y = 0; z.z = 0; z.w = 0;
        *(ushort4*)(yr) = one;
#pragma unroll
        for (int q = 1; q < 8; ++q) *(ushort4*)(yr + q * 4) = z;
    }
    __syncthreads();

    const int lane = t & 63, wave = t >> 6;
    const int n = lane & 15, quad = lane >> 4;
    const int m0 = wave * 16;

    f32x4 acc = {0.f, 0.f, 0.f, 0.f};
#pragma unroll
    for (int k = 0; k < 8; ++k) {
        short8 af = *(const short8*)(w1b + (m0 + n) * 256 + k * 32 + quad * 8);
        short8 bf = *(const short8*)(&xt[n * 264 + k * 32 + quad * 8]);
        acc = __builtin_amdgcn_mfma_f32_16x16x32_bf16(af, bf, acc, 0, 0, 0);
    }
    ushort4 pack;
    unsigned short pk[4];
#pragma unroll
    for (int r = 0; r < 4; ++r) {
        int m = m0 + quad * 4 + r;
        float2 ss = *(const float2*)(scsh + m * 2);
        pk[r] = f2bf(fmaxf(acc[r] * ss.x + ss.y, 0.f));
    }
    pack.x = pk[0]; pack.y = pk[1]; pack.z = pk[2]; pack.w = pk[3];
    *(ushort4*)(ytb + (size_t)(px0 + n) * YSTR + m0 + quad * 4) = pack;
}

// One (batch, chunk) per block: w-gen (K=96 MFMA) + involution, single barrier.
__global__ __launch_bounds__(256, 4) void kmain(
    const float* __restrict__ x, const unsigned short* __restrict__ w2b96,
    const unsigned short* __restrict__ ytb, float* __restrict__ out)
{
    __shared__ __align__(16) char smem[39936];
    uint2* xsb = (uint2*)smem;                             // 16*101 u2 = 12928 B
    unsigned short* wgt = (unsigned short*)(smem + XS_OFF);// 16*844 ush = 27008 B

    const int t = threadIdx.x;
    const int pix = t & 15, sub = t >> 4;
    const int lane = t & 63, wave = t >> 6;
    const int z = blockIdx.z;
    const int b = z >> 2, chunk = z & 3;
    const int h0 = blockIdx.y * 4, w0 = blockIdx.x * 4;
    const int ph = pix >> 2, pw = pix & 3;
    const int h = h0 + ph, w = w0 + pw;
    const int n = lane & 15, quad = lane >> 4;
    const int sg = t & 15, sr = t >> 4;       // staging job (t<160)

    // 1. prefetch x footprint for this chunk (HBM, in flight during B-frag/w-gen setup)
    float4 rv[4][3];
    if (t < 160) loadx(x, b, chunk, sg, sr, h0, w0, rv);

    // 2. B-fragments from ytb (L2-resident; K=96 incl. b2 lane)
    const int Pn = b * HW + (h0 + (n >> 2)) * 56 + w0 + (n & 3);
    const unsigned short* yrp = ytb + (size_t)Pn * YSTR + quad * 8;
    const short8 bf0 = *(const short8*)(yrp);
    const short8 bf1 = *(const short8*)(yrp + 32);
    const short8 bf2 = *(const short8*)(yrp + 64);

    // 3. zero wgt pad taps (k=49..51)
    for (int i = t; i < 768; i += 256) {
        int p = i / 48, rem = i - p * 48;
        int g = rem / 3, kk = 49 + (rem - g * 3);
        wgt[p * WSTR + g * 52 + kk] = 0;
    }

    // 4. commit footprint to LDS as packed bf16x4 (frees rv registers)
    if (t < 160) {
        uint2* dst = &xsb[sg * 101 + sr * 10];
#pragma unroll
        for (int s = 0; s < 10; ++s) {
            int qq = (s + 1) >> 2, e = (s + 1) & 3;
            uint2 pkx;
            pkx.x = (unsigned int)f2bf(fget(rv[0][qq], e)) |
                    ((unsigned int)f2bf(fget(rv[1][qq], e)) << 16);
            pkx.y = (unsigned int)f2bf(fget(rv[2][qq], e)) |
                    ((unsigned int)f2bf(fget(rv[3][qq], e)) << 16);
            dst[s] = pkx;
        }
    }

    // 5. weight generation: 784 ch x 16 px, K=96 MFMA, depth-1 pipelined A-loads
    const int c0 = chunk * 784;
    {
        const unsigned short* ap = w2b96 + (size_t)(c0 + wave * 16 + n) * 96 + quad * 8;
        short8 af0 = *(const short8*)(ap);
        short8 af1 = *(const short8*)(ap + 32);
        short8 af2 = *(const short8*)(ap + 64);
        for (int tile = wave; tile < 49; tile += 4) {
            short8 ca0 = af0, ca1 = af1, ca2 = af2;
            if (tile + 4 < 49) {
                const unsigned short* ap2 =
                    w2b96 + (size_t)(c0 + (tile + 4) * 16 + n) * 96 + quad * 8;
                af0 = *(const short8*)(ap2);
                af1 = *(const short8*)(ap2 + 32);
                af2 = *(const short8*)(ap2 + 64);
            }
            f32x4 acc = {0.f, 0.f, 0.f, 0.f};
            acc = __builtin_amdgcn_mfma_f32_16x16x32_bf16(ca0, bf0, acc, 0, 0, 0);
            acc = __builtin_amdgcn_mfma_f32_16x16x32_bf16(ca1, bf1, acc, 0, 0, 0);
            acc = __builtin_amdgcn_mfma_f32_16x16x32_bf16(ca2, bf2, acc, 0, 0, 0);
            int rbase = tile * 16 + quad * 4;
#pragma unroll
            for (int r = 0; r < 4; ++r) {
                int chl = rbase + r;
                int g = chl / 49;
                int kk = chl - g * 49;
                wgt[n * WSTR + g * 52 + kk] = f2bf(acc[r]);
            }
        }
    }
    __syncthreads();    // the only barrier: xsb + wgt ready

    // 6. involution: thread = (group sub, 4 channels, pixel pix)
    const unsigned short* wr = &wgt[pix * WSTR + sub * 52];
    const uint2* xr = &xsb[sub * 101];
    float a0 = 0.f, a1 = 0.f, a2 = 0.f, a3 = 0.f;
#pragma unroll
    for (int kq = 0; kq < 13; ++kq) {
        uint2 wp = *(const uint2*)(wr + kq * 4);
#pragma unroll
        for (int e = 0; e < 4; ++e) {
            int k = kq * 4 + e;
            if (k < 49) {
                unsigned int uw = (e < 2) ? wp.x : wp.y;
                unsigned int ub = (e & 1) ? (uw & 0xffff0000u) : (uw << 16);
                float wv = __uint_as_float(ub);
                int ki = k / 7, kj = k - ki * 7;       // compile-time
                uint2 xp = xr[(ph + ki) * 10 + (pw + kj)];
                a0 += wv * __uint_as_float(xp.x << 16);
                a1 += wv * __uint_as_float(xp.x & 0xffff0000u);
                a2 += wv * __uint_as_float(xp.y << 16);
                a3 += wv * __uint_as_float(xp.y & 0xffff0000u);
            }
        }
    }
    size_t ob = ((size_t)b * 256 + chunk * 64 + sub * 4) * HW + h * 56 + w;
    out[ob] = a0;
    out[ob + HW] = a1;
    out[ob + 2 * HW] = a2;
    out[ob + 3 * HW] = a3;
}

extern "C" void kernel_launch(void* const* d_in, const int* in_sizes, int n_in,
                              void* d_out, int out_size, void* d_ws, size_t ws_size,
                              hipStream_t stream) {
    const float* x     = (const float*)d_in[0];
    const float* w1    = (const float*)d_in[1];
    const float* b1    = (const float*)d_in[2];
    const float* gamma = (const float*)d_in[3];
    const float* beta  = (const float*)d_in[4];
    const float* mean  = (const float*)d_in[5];
    const float* var   = (const float*)d_in[6];
    const float* w2    = (const float*)d_in[7];
    const float* b2    = (const float*)d_in[8];
    float* out = (float*)d_out;

    unsigned short* ytb   = (unsigned short*)d_ws;         // 12544*96 = 1204224 ush
    unsigned short* w2b96 = ytb + (size_t)NPX * YSTR;      // 3136*96  = 301056 ush
    unsigned short* w1b   = w2b96 + 3136 * 96;             // 16384 ush
    float* scsh = (float*)(w1b + 16384);                   // 128 floats

    hipLaunchKernelGGL(kprep, dim3(213), dim3(256), 0, stream,
                       w2, b2, w1, b1, gamma, beta, mean, var, w2b96, w1b, scsh);
    hipLaunchKernelGGL(ky2, dim3(784), dim3(256), 0, stream, x, w1b, scsh, ytb);
    hipLaunchKernelGGL(kmain, dim3(14, 14, 16), dim3(256), 0, stream,
                       x, w2b96, ytb, out);
}